// Round 1
// 110.900 us; speedup vs baseline: 1.0380x; 1.0380x over previous
//
#include <hip/hip_runtime.h>
#include <hip/hip_bf16.h>

#define S_LEN 4096
#define EMB   256
#define NHEAD 8
#define HDIM  32
#define WIN   64
#define BATCH 2

typedef __attribute__((ext_vector_type(8))) short short8;
typedef __attribute__((ext_vector_type(4))) float floatx4;
typedef unsigned short u16;
typedef unsigned int   u32;

// ---- split-precision bf16, packed as u32 = (hi<<16)|lo; x = hi + lo + O(2^-18 |x|) ----
static __device__ __forceinline__ u32 bf16_rn(float x) {
    u32 u = __float_as_uint(x);
    return (u + 0x7FFFu + ((u >> 16) & 1u)) >> 16;
}
static __device__ __forceinline__ u32 packsplit(float x) {
    const u32 hi = bf16_rn(x);
    const float hf = __uint_as_float(hi << 16);
    const u32 lo = bf16_rn(x - hf);
    return (hi << 16) | lo;
}
// two packed elems -> (hi0,hi1) u32 and (lo0,lo1) u32 (little-endian u16 order)
static __device__ __forceinline__ void unpack_pair(u32 p0, u32 p1, u32& h, u32& l) {
    h = (p0 >> 16) | (p1 & 0xFFFF0000u);
    l = (p0 & 0xFFFFu) | (p1 << 16);
}
static __device__ __forceinline__ void unpack8(uint4 a, uint4 b, uint4& h, uint4& l) {
    unpack_pair(a.x, a.y, h.x, l.x);
    unpack_pair(a.z, a.w, h.y, l.y);
    unpack_pair(b.x, b.y, h.z, l.z);
    unpack_pair(b.z, b.w, h.w, l.w);
}

// ============ pre-pass: fp32 -> packed split-bf16 for X, in_proj_w, out_w ============
#define NX4 524288   // 8192*256/4
#define NW4 49152    // 768*256/4
#define NO4 16384    // 256*256/4

__global__ __launch_bounds__(256) void convert_kernel(
    const float* __restrict__ X, const float* __restrict__ Wi, const float* __restrict__ Wo,
    u32* __restrict__ Xp, u32* __restrict__ Wip, u32* __restrict__ Wop)
{
    const int i = blockIdx.x * 256 + threadIdx.x;
    const float* src; u32* dst; int off;
    if (i < NX4)            { src = X;  dst = Xp;  off = i; }
    else if (i < NX4 + NW4) { src = Wi; dst = Wip; off = i - NX4; }
    else                    { src = Wo; dst = Wop; off = i - NX4 - NW4; }
    const float4 v = *(const float4*)(src + (size_t)off * 4);
    uint4 o;
    o.x = packsplit(v.x); o.y = packsplit(v.y);
    o.z = packsplit(v.z); o.w = packsplit(v.w);
    *(uint4*)(dst + (size_t)off * 4) = o;
}

// ============ QKV GEMM: C[8192,768] = X * W^T, packed-u32 in/out ============
#define LDA 40  // u16 row stride: 80B, 16B-aligned, 2-way-free

__global__ __launch_bounds__(256) void qkv_proj_kernel(
    const u32* __restrict__ Xp, const u32* __restrict__ Wp,
    const float* __restrict__ bias,
    u32* __restrict__ Qp, u32* __restrict__ Kp, u32* __restrict__ Vp)
{
    __shared__ __align__(16) u16 Ah[128 * LDA], Al[128 * LDA];
    __shared__ __align__(16) u16 Bh[64 * LDA],  Bl[64 * LDA];
    const int tid = threadIdx.x;
    const int m0 = blockIdx.y * 128, n0 = blockIdx.x * 64;
    const int srow = tid >> 2, sc = tid & 3;        // staging: row, 8-elem col
    const int lane = tid & 63, wv = tid >> 6;
    const int wm = (wv >> 1) * 64, wn = (wv & 1) * 32;
    const int lm = lane & 15, kq = lane >> 4;

    uint4 pA[2][2], pB[2];
#pragma unroll
    for (int r = 0; r < 2; ++r) {
        const u32* base = Xp + (size_t)(m0 + srow + r * 64) * EMB + sc * 8;
        pA[r][0] = *(const uint4*)base;
        pA[r][1] = *(const uint4*)(base + 4);
    }
    {
        const u32* base = Wp + (size_t)(n0 + srow) * EMB + sc * 8;
        pB[0] = *(const uint4*)base;
        pB[1] = *(const uint4*)(base + 4);
    }

    floatx4 acc[4][2] = {};
    for (int t = 0; t < 8; ++t) {
        __syncthreads();
#pragma unroll
        for (int r = 0; r < 2; ++r) {
            uint4 h, l;
            unpack8(pA[r][0], pA[r][1], h, l);
            *(uint4*)&Ah[(srow + r * 64) * LDA + sc * 8] = h;
            *(uint4*)&Al[(srow + r * 64) * LDA + sc * 8] = l;
        }
        {
            uint4 h, l;
            unpack8(pB[0], pB[1], h, l);
            *(uint4*)&Bh[srow * LDA + sc * 8] = h;
            *(uint4*)&Bl[srow * LDA + sc * 8] = l;
        }
        __syncthreads();
        if (t < 7) {
            const int k0 = (t + 1) * 32;
#pragma unroll
            for (int r = 0; r < 2; ++r) {
                const u32* base = Xp + (size_t)(m0 + srow + r * 64) * EMB + k0 + sc * 8;
                pA[r][0] = *(const uint4*)base;
                pA[r][1] = *(const uint4*)(base + 4);
            }
            const u32* base = Wp + (size_t)(n0 + srow) * EMB + k0 + sc * 8;
            pB[0] = *(const uint4*)base;
            pB[1] = *(const uint4*)(base + 4);
        }
        short8 a_h[4], a_l[4], b_h[2], b_l[2];
#pragma unroll
        for (int mt = 0; mt < 4; ++mt) {
            a_h[mt] = *(const short8*)&Ah[(wm + mt * 16 + lm) * LDA + kq * 8];
            a_l[mt] = *(const short8*)&Al[(wm + mt * 16 + lm) * LDA + kq * 8];
        }
#pragma unroll
        for (int nt = 0; nt < 2; ++nt) {
            b_h[nt] = *(const short8*)&Bh[(wn + nt * 16 + lm) * LDA + kq * 8];
            b_l[nt] = *(const short8*)&Bl[(wn + nt * 16 + lm) * LDA + kq * 8];
        }
#pragma unroll
        for (int mt = 0; mt < 4; ++mt)
#pragma unroll
            for (int nt = 0; nt < 2; ++nt) {
                acc[mt][nt] = __builtin_amdgcn_mfma_f32_16x16x32_bf16(a_h[mt], b_h[nt], acc[mt][nt], 0, 0, 0);
                acc[mt][nt] = __builtin_amdgcn_mfma_f32_16x16x32_bf16(a_h[mt], b_l[nt], acc[mt][nt], 0, 0, 0);
                acc[mt][nt] = __builtin_amdgcn_mfma_f32_16x16x32_bf16(a_l[mt], b_h[nt], acc[mt][nt], 0, 0, 0);
            }
    }
    // epilogue: packed u32 stores, 4B/lane x 16 consecutive d -> full 64B lines
#pragma unroll
    for (int nt = 0; nt < 2; ++nt) {
        const int f = n0 + wn + nt * 16 + lm;
        const int which = f >> 8;
        const int h = (f & 255) >> 5, d = f & 31;
        u32* dst = (which == 0) ? Qp : ((which == 1) ? Kp : Vp);
        const float sc2 = (which == 0) ? 0.17677669529663687f : 1.0f;
        const float bf = bias[f];
#pragma unroll
        for (int mt = 0; mt < 4; ++mt)
#pragma unroll
            for (int r = 0; r < 4; ++r) {
                const int m = m0 + wm + mt * 16 + kq * 4 + r;
                const int b = m >> 12, s = m & (S_LEN - 1);
                dst[(((size_t)b * NHEAD + h) * S_LEN + s) * HDIM + d]
                    = packsplit((acc[mt][nt][r] + bf) * sc2);
            }
    }
}

// ============ OUT GEMM: out[8192,256] = Ab * Wo^T + b ============
// 64x64 tiles, grid (4,128)=512 blocks -> 2 blocks/CU (was 1: no latency hiding)
__global__ __launch_bounds__(256) void out_proj_kernel(
    const u32* __restrict__ Abp, const u32* __restrict__ Wp,
    const float* __restrict__ bias, float* __restrict__ C)
{
    __shared__ __align__(16) u16 Ah[64 * LDA], Al[64 * LDA];
    __shared__ __align__(16) u16 Bh[64 * LDA], Bl[64 * LDA];
    const int tid = threadIdx.x;
    const int m0 = blockIdx.y * 64, n0 = blockIdx.x * 64;
    const int srow = tid >> 2, sc = tid & 3;
    const int lane = tid & 63, wv = tid >> 6;
    const int wm = (wv >> 1) * 32, wn = (wv & 1) * 32;
    const int lm = lane & 15, kq = lane >> 4;

    uint4 pA[2], pB[2];
    {
        const u32* base = Abp + (size_t)(m0 + srow) * EMB + sc * 8;
        pA[0] = *(const uint4*)base;
        pA[1] = *(const uint4*)(base + 4);
    }
    {
        const u32* base = Wp + (size_t)(n0 + srow) * EMB + sc * 8;
        pB[0] = *(const uint4*)base;
        pB[1] = *(const uint4*)(base + 4);
    }

    floatx4 acc[2][2] = {};
    for (int t = 0; t < 8; ++t) {
        __syncthreads();
        {
            uint4 h, l;
            unpack8(pA[0], pA[1], h, l);
            *(uint4*)&Ah[srow * LDA + sc * 8] = h;
            *(uint4*)&Al[srow * LDA + sc * 8] = l;
        }
        {
            uint4 h, l;
            unpack8(pB[0], pB[1], h, l);
            *(uint4*)&Bh[srow * LDA + sc * 8] = h;
            *(uint4*)&Bl[srow * LDA + sc * 8] = l;
        }
        __syncthreads();
        if (t < 7) {
            const int k0 = (t + 1) * 32;
            {
                const u32* base = Abp + (size_t)(m0 + srow) * EMB + k0 + sc * 8;
                pA[0] = *(const uint4*)base;
                pA[1] = *(const uint4*)(base + 4);
            }
            const u32* base = Wp + (size_t)(n0 + srow) * EMB + k0 + sc * 8;
            pB[0] = *(const uint4*)base;
            pB[1] = *(const uint4*)(base + 4);
        }
        short8 a_h[2], a_l[2], b_h[2], b_l[2];
#pragma unroll
        for (int mt = 0; mt < 2; ++mt) {
            a_h[mt] = *(const short8*)&Ah[(wm + mt * 16 + lm) * LDA + kq * 8];
            a_l[mt] = *(const short8*)&Al[(wm + mt * 16 + lm) * LDA + kq * 8];
        }
#pragma unroll
        for (int nt = 0; nt < 2; ++nt) {
            b_h[nt] = *(const short8*)&Bh[(wn + nt * 16 + lm) * LDA + kq * 8];
            b_l[nt] = *(const short8*)&Bl[(wn + nt * 16 + lm) * LDA + kq * 8];
        }
#pragma unroll
        for (int mt = 0; mt < 2; ++mt)
#pragma unroll
            for (int nt = 0; nt < 2; ++nt) {
                acc[mt][nt] = __builtin_amdgcn_mfma_f32_16x16x32_bf16(a_h[mt], b_h[nt], acc[mt][nt], 0, 0, 0);
                acc[mt][nt] = __builtin_amdgcn_mfma_f32_16x16x32_bf16(a_h[mt], b_l[nt], acc[mt][nt], 0, 0, 0);
                acc[mt][nt] = __builtin_amdgcn_mfma_f32_16x16x32_bf16(a_l[mt], b_h[nt], acc[mt][nt], 0, 0, 0);
            }
    }
#pragma unroll
    for (int nt = 0; nt < 2; ++nt) {
        const int f = n0 + wn + nt * 16 + lm;
        const float bf = bias[f];
#pragma unroll
        for (int mt = 0; mt < 2; ++mt)
#pragma unroll
            for (int r = 0; r < 4; ++r) {
                const int m = m0 + wm + mt * 16 + kq * 4 + r;
                C[(size_t)m * EMB + f] = acc[mt][nt][r] + bf;
            }
    }
}

// ================= Banded attention (swapped-QK, in-register softmax) =================
// mfma(K, Q): lane (lm,quad) holds scores for q = lm, keys = nt*16 + quad*4 + r.
// Softmax reduces via shfl_xor(16/32); P stays in registers. PV uses a k-permutation
// pi(quad*8+j) = (2ks+(j>>2))*16 + quad*4 + (j&3) applied to BOTH operands, so the
// A-fragment is the lane's own packed P words (zero shuffles) and the B-side reads
// two 8B chunks from Vt per fragment.
#define AKS 40   // K row stride (u16)
#define AVS 200  // Vt row stride (u16)

__global__ __launch_bounds__(256) void local_attn_kernel(
    const u32* __restrict__ Qp, const u32* __restrict__ Kp,
    const u32* __restrict__ Vp, u32* __restrict__ Abp)
{
    __shared__ __align__(16) u16 Kh[192 * AKS], Kl[192 * AKS];
    __shared__ __align__(16) u16 Vt[32 * AVS];

    const int tid = threadIdx.x;
    const int q0 = blockIdx.x * 64;
    const int h = blockIdx.y, b = blockIdx.z;
    const int jmin = max(0, q0 - WIN);
    const int jmax = min(S_LEN - 1, q0 + 63 + WIN);
    const int nk = jmax - jmin + 1;                  // <= 192
    const size_t bhS = ((size_t)b * NHEAD + h) * S_LEN;
    const size_t qoff = (bhS + q0) * HDIM;
    const size_t koff = (bhS + jmin) * HDIM;

    const int lane = tid & 63, wv = tid >> 6;
    const int lm = lane & 15, quad = lane >> 4;
    const int qbase = wv * 16;

    // Q to registers: each lane owns Q[q0+qbase+lm][quad*8 .. +7] (hi+lo)
    const u32* qb = Qp + qoff + (size_t)(qbase + lm) * HDIM + quad * 8;
    const uint4 qp0 = *(const uint4*)qb;
    const uint4 qp1 = *(const uint4*)(qb + 4);

    const int srow = tid >> 2, sc = tid & 3;
    // stage K (192 slots): 3 passes, tail clamped (masked later)
#pragma unroll
    for (int r = 0; r < 3; ++r) {
        const int t = srow + r * 64;
        const int tc = min(t, nk - 1);
        const u32* base = Kp + koff + (size_t)tc * HDIM + sc * 8;
        uint4 h4, l4;
        unpack8(*(const uint4*)base, *(const uint4*)(base + 4), h4, l4);
        *(uint4*)&Kh[t * AKS + sc * 8] = h4;
        *(uint4*)&Kl[t * AKS + sc * 8] = l4;
    }
    // stage V transposed (hi halves only): Vt[dim][slot]
#pragma unroll
    for (int r = 0; r < 3; ++r) {
        const int t = srow + r * 64;
        const int tc = min(t, nk - 1);
        const u32* base = Vp + koff + (size_t)tc * HDIM + sc * 8;
        const uint4 v0 = *(const uint4*)base;
        const uint4 v1 = *(const uint4*)(base + 4);
        const int d0 = sc * 8;
        Vt[(d0 + 0) * AVS + t] = (u16)(v0.x >> 16);
        Vt[(d0 + 1) * AVS + t] = (u16)(v0.y >> 16);
        Vt[(d0 + 2) * AVS + t] = (u16)(v0.z >> 16);
        Vt[(d0 + 3) * AVS + t] = (u16)(v0.w >> 16);
        Vt[(d0 + 4) * AVS + t] = (u16)(v1.x >> 16);
        Vt[(d0 + 5) * AVS + t] = (u16)(v1.y >> 16);
        Vt[(d0 + 6) * AVS + t] = (u16)(v1.z >> 16);
        Vt[(d0 + 7) * AVS + t] = (u16)(v1.w >> 16);
    }

    // unpack Q while staging lands
    short8 qh, ql;
    {
        uint4 h4, l4;
        unpack8(qp0, qp1, h4, l4);
        qh = *(const short8*)&h4;
        ql = *(const short8*)&l4;
    }

    __syncthreads();

    // band-aware tile window: wave's valid slots are [wv*16+off, wv*16+143+off],
    // off = q0-WIN-jmin (0 interior, -64 at q0=0) -> 10 tiles suffice (vs 12)
    const int tb = max(0, ((wv >> 1) << 1) + (min(q0 - WIN, 0) >> 4));

    floatx4 sacc[10];
#pragma unroll
    for (int i = 0; i < 10; ++i) {
        const int nt = tb + i;
        const short8 kh = *(const short8*)&Kh[(nt * 16 + lm) * AKS + quad * 8];
        const short8 kl = *(const short8*)&Kl[(nt * 16 + lm) * AKS + quad * 8];
        floatx4 a = {};
        a = __builtin_amdgcn_mfma_f32_16x16x32_bf16(kh, qh, a, 0, 0, 0);
        a = __builtin_amdgcn_mfma_f32_16x16x32_bf16(kh, ql, a, 0, 0, 0);
        a = __builtin_amdgcn_mfma_f32_16x16x32_bf16(kl, qh, a, 0, 0, 0);
        sacc[i] = a;
    }

    // mask + row max (row = this lane's q = q0+qbase+lm)
    const int qr = q0 + qbase + lm;
    float mx = -1e30f;
#pragma unroll
    for (int i = 0; i < 10; ++i) {
        const int sbase = (tb + i) * 16 + quad * 4;
#pragma unroll
        for (int r = 0; r < 4; ++r) {
            const int slot = sbase + r;
            const int keyg = jmin + slot;
            const bool valid = (slot < nk) && (keyg >= qr - WIN) && (keyg <= qr + WIN);
            const float sv = valid ? sacc[i][r] : -1e30f;
            sacc[i][r] = sv;
            mx = fmaxf(mx, sv);
        }
    }
    mx = fmaxf(mx, __shfl_xor(mx, 16));
    mx = fmaxf(mx, __shfl_xor(mx, 32));

    // exp + sum + pack P to bf16 in-register (unnormalized; rl applied at epilogue)
    float l = 0.f;
    u32 pk_[20];
#pragma unroll
    for (int i = 0; i < 10; ++i) {
        const float p0 = __expf(sacc[i][0] - mx);
        const float p1 = __expf(sacc[i][1] - mx);
        const float p2 = __expf(sacc[i][2] - mx);
        const float p3 = __expf(sacc[i][3] - mx);
        l += (p0 + p1) + (p2 + p3);
        pk_[2 * i]     = bf16_rn(p0) | (bf16_rn(p1) << 16);
        pk_[2 * i + 1] = bf16_rn(p2) | (bf16_rn(p3) << 16);
    }
    l += __shfl_xor(l, 16);
    l += __shfl_xor(l, 32);
    const float rl = 1.f / l;

    // PV with k-permutation pi; ks range [kb, kb+5) covers exactly tiles [tb, tb+10)
    const int kb = tb >> 1;
    floatx4 oacc[2] = {};
#pragma unroll
    for (int i = 0; i < 5; ++i) {
        const int ks = kb + i;
        uint4 aw;
        aw.x = pk_[4 * i + 0];
        aw.y = pk_[4 * i + 1];
        aw.z = pk_[4 * i + 2];
        aw.w = pk_[4 * i + 3];
        const short8 ap = *(const short8*)&aw;
        const int sb = ks * 32 + quad * 4;
        const uint2 e0 = *(const uint2*)&Vt[lm * AVS + sb];
        const uint2 o0 = *(const uint2*)&Vt[lm * AVS + sb + 16];
        const uint2 e1 = *(const uint2*)&Vt[(16 + lm) * AVS + sb];
        const uint2 o1 = *(const uint2*)&Vt[(16 + lm) * AVS + sb + 16];
        uint4 bw0; bw0.x = e0.x; bw0.y = e0.y; bw0.z = o0.x; bw0.w = o0.y;
        uint4 bw1; bw1.x = e1.x; bw1.y = e1.y; bw1.z = o1.x; bw1.w = o1.y;
        const short8 bv0 = *(const short8*)&bw0;
        const short8 bv1 = *(const short8*)&bw1;
        oacc[0] = __builtin_amdgcn_mfma_f32_16x16x32_bf16(ap, bv0, oacc[0], 0, 0, 0);
        oacc[1] = __builtin_amdgcn_mfma_f32_16x16x32_bf16(ap, bv1, oacc[1], 0, 0, 0);
    }

    // epilogue: lane (lm,quad) holds O[q=quad*4+r][d=nt*16+lm]; fetch rl for those rows
    float rlr[4];
#pragma unroll
    for (int r = 0; r < 4; ++r) rlr[r] = __shfl(rl, quad * 4 + r);
#pragma unroll
    for (int nt = 0; nt < 2; ++nt)
#pragma unroll
        for (int r = 0; r < 4; ++r) {
            const int qrow = qbase + quad * 4 + r;
            Abp[((size_t)b * S_LEN + q0 + qrow) * EMB + h * HDIM + nt * 16 + lm]
                = packsplit(oacc[nt][r] * rlr[r]);
        }
}

extern "C" void kernel_launch(void* const* d_in, const int* in_sizes, int n_in,
                              void* d_out, int out_size, void* d_ws, size_t ws_size,
                              hipStream_t stream) {
    const float* x  = (const float*)d_in[0];
    const float* wi = (const float*)d_in[1];
    const float* bi = (const float*)d_in[2];
    const float* wo = (const float*)d_in[3];
    const float* bo = (const float*)d_in[4];
    float* out = (float*)d_out;

    const size_t per = (size_t)BATCH * NHEAD * S_LEN * HDIM; // 2,097,152
    u32* p = (u32*)d_ws;
    u32* Xp  = p; p += per;
    u32* Wip = p; p += 768 * EMB;
    u32* Wop = p; p += EMB * EMB;
    u32* Qp  = p; p += per;
    u32* Kp  = p; p += per;
    u32* Vp  = p; p += per;
    u32* Abp = p; p += per;

    convert_kernel<<<dim3((NX4 + NW4 + NO4) / 256), 256, 0, stream>>>(
        x, wi, wo, Xp, Wip, Wop);
    qkv_proj_kernel<<<dim3(768 / 64, 8192 / 128), 256, 0, stream>>>(
        Xp, Wip, bi, Qp, Kp, Vp);
    local_attn_kernel<<<dim3(S_LEN / 64, NHEAD, BATCH), 256, 0, stream>>>(
        Qp, Kp, Vp, Abp);
    out_proj_kernel<<<dim3(256 / 64, 8192 / 64), 256, 0, stream>>>(
        Abp, Wop, bo, out);
}

// Round 2
// 108.200 us; speedup vs baseline: 1.0639x; 1.0250x over previous
//
#include <hip/hip_runtime.h>
#include <hip/hip_bf16.h>

#define S_LEN 4096
#define EMB   256
#define NHEAD 8
#define HDIM  32
#define WIN   64
#define BATCH 2

typedef __attribute__((ext_vector_type(8))) short short8;
typedef __attribute__((ext_vector_type(4))) float floatx4;
typedef __attribute__((ext_vector_type(4))) unsigned short ushort4v;
typedef unsigned short u16;
typedef unsigned int   u32;

// ---- split-precision bf16 helpers: x = hi + lo + O(2^-18 |x|) ----
static __device__ __forceinline__ u32 bf16_rn(float x) {
    u32 u = __float_as_uint(x);
    return (u + 0x7FFFu + ((u >> 16) & 1u)) >> 16;
}

// async global->LDS, 16B per lane; LDS dest = wave-uniform base + lane*16
static __device__ __forceinline__ void gload16(const u16* g, u16* l) {
    __builtin_amdgcn_global_load_lds(
        (const __attribute__((address_space(1))) void*)g,
        (__attribute__((address_space(3))) void*)l, 16, 0, 0);
}

// ============ pre-pass: fp32 -> separate hi/lo bf16 planes ============
#define NX4 524288   // 8192*256/4
#define NW4 49152    // 768*256/4
#define NO4 16384    // 256*256/4

__global__ __launch_bounds__(256) void convert_kernel(
    const float* __restrict__ X, const float* __restrict__ Wi, const float* __restrict__ Wo,
    u16* __restrict__ Xh, u16* __restrict__ Xl,
    u16* __restrict__ Wih, u16* __restrict__ Wil,
    u16* __restrict__ Woh, u16* __restrict__ Wol)
{
    const int i = blockIdx.x * 256 + threadIdx.x;
    const float* src; u16 *dh, *dl; int off;
    if (i < NX4)            { src = X;  dh = Xh;  dl = Xl;  off = i; }
    else if (i < NX4 + NW4) { src = Wi; dh = Wih; dl = Wil; off = i - NX4; }
    else                    { src = Wo; dh = Woh; dl = Wol; off = i - NX4 - NW4; }
    const float4 v = *(const float4*)(src + (size_t)off * 4);
    ushort4v h, l;
    {
        u32 hb;
        hb = bf16_rn(v.x); h.x = (u16)hb; l.x = (u16)bf16_rn(v.x - __uint_as_float(hb << 16));
        hb = bf16_rn(v.y); h.y = (u16)hb; l.y = (u16)bf16_rn(v.y - __uint_as_float(hb << 16));
        hb = bf16_rn(v.z); h.z = (u16)hb; l.z = (u16)bf16_rn(v.z - __uint_as_float(hb << 16));
        hb = bf16_rn(v.w); h.w = (u16)hb; l.w = (u16)bf16_rn(v.w - __uint_as_float(hb << 16));
    }
    *(ushort4v*)(dh + (size_t)off * 4) = h;
    *(ushort4v*)(dl + (size_t)off * 4) = l;
}

// ============ QKV GEMM: C[8192,768] = X * W^T, hi/lo planes, gload_lds staging ============
#define BK 32

__global__ __launch_bounds__(256) void qkv_proj_kernel(
    const u16* __restrict__ Xh, const u16* __restrict__ Xl,
    const u16* __restrict__ Wh, const u16* __restrict__ Wl,
    const float* __restrict__ bias,
    u16* __restrict__ Qh, u16* __restrict__ Ql,
    u16* __restrict__ Kh, u16* __restrict__ Kl,
    u16* __restrict__ Vh)
{
    __shared__ __align__(16) u16 SA[2][2][128 * BK];  // [buf][hi/lo], linear [row][32]
    __shared__ __align__(16) u16 SB[2][2][64 * BK];

    const int tid = threadIdx.x;
    // XCD-aware bijective swizzle (768 % 8 == 0)
    const int wg0 = blockIdx.y * 12 + blockIdx.x;
    const int wg = (wg0 & 7) * 96 + (wg0 >> 3);
    const int n0 = (wg % 12) * 64, m0 = (wg / 12) * 128;
    const int lane = tid & 63, wv = tid >> 6;
    const int lm = lane & 15, kq = lane >> 4;
    const int gr = lane >> 2;                                  // row within 16-row chunk
    const int gc = ((lane & 3) ^ ((lane >> 3) & 3)) * 8;       // inverse-swizzled src col (u16)
    const int swz = (lm >> 1) & 3;                             // read-side slot swizzle
    const int wm = (wv >> 1) * 64, wn = (wv & 1) * 32;

    auto stage = [&](int buf, int k0) {
#pragma unroll
        for (int cc = 0; cc < 2; ++cc) {
            const int c = 2 * wv + cc;                         // A chunk (16 rows)
            const size_t grow = (size_t)(m0 + 16 * c + gr) * EMB + k0 + gc;
            gload16(Xh + grow, &SA[buf][0][c * 512]);
            gload16(Xl + grow, &SA[buf][1][c * 512]);
        }
        const size_t brow = (size_t)(n0 + 16 * wv + gr) * EMB + k0 + gc;
        gload16(Wh + brow, &SB[buf][0][wv * 512]);
        gload16(Wl + brow, &SB[buf][1][wv * 512]);
    };

    floatx4 acc[4][2] = {};
    stage(0, 0);
    __syncthreads();
    int cur = 0;
    for (int t = 0; t < 8; ++t) {
        if (t < 7) stage(cur ^ 1, (t + 1) * 32);
        short8 a_h[4], a_l[4], b_h[2], b_l[2];
#pragma unroll
        for (int mt = 0; mt < 4; ++mt) {
            const int ro = (wm + mt * 16 + lm) * BK + (kq ^ swz) * 8;
            a_h[mt] = *(const short8*)&SA[cur][0][ro];
            a_l[mt] = *(const short8*)&SA[cur][1][ro];
        }
#pragma unroll
        for (int nt = 0; nt < 2; ++nt) {
            const int ro = (wn + nt * 16 + lm) * BK + (kq ^ swz) * 8;
            b_h[nt] = *(const short8*)&SB[cur][0][ro];
            b_l[nt] = *(const short8*)&SB[cur][1][ro];
        }
#pragma unroll
        for (int mt = 0; mt < 4; ++mt)
#pragma unroll
            for (int nt = 0; nt < 2; ++nt) {
                acc[mt][nt] = __builtin_amdgcn_mfma_f32_16x16x32_bf16(a_h[mt], b_h[nt], acc[mt][nt], 0, 0, 0);
                acc[mt][nt] = __builtin_amdgcn_mfma_f32_16x16x32_bf16(a_h[mt], b_l[nt], acc[mt][nt], 0, 0, 0);
                acc[mt][nt] = __builtin_amdgcn_mfma_f32_16x16x32_bf16(a_l[mt], b_h[nt], acc[mt][nt], 0, 0, 0);
            }
        __syncthreads();   // drains stage loads (vmcnt) + frag reads (lgkm)
        cur ^= 1;
    }
    // epilogue: hi/lo plane stores (V: hi only — attn never reads V-lo)
#pragma unroll
    for (int nt = 0; nt < 2; ++nt) {
        const int f = n0 + wn + nt * 16 + lm;
        const int which = f >> 8;
        const int hh = (f & 255) >> 5, d = f & 31;
        u16* dh = (which == 0) ? Qh : ((which == 1) ? Kh : Vh);
        u16* dl = (which == 0) ? Ql : Kl;
        const float sc2 = (which == 0) ? 0.17677669529663687f : 1.0f;
        const float bf = bias[f];
#pragma unroll
        for (int mt = 0; mt < 4; ++mt)
#pragma unroll
            for (int r = 0; r < 4; ++r) {
                const int m = m0 + wm + mt * 16 + kq * 4 + r;
                const int b = m >> 12, s = m & (S_LEN - 1);
                const size_t idx = (((size_t)b * NHEAD + hh) * S_LEN + s) * HDIM + d;
                const float val = (acc[mt][nt][r] + bf) * sc2;
                const u32 hbits = bf16_rn(val);
                dh[idx] = (u16)hbits;
                if (which != 2)
                    dl[idx] = (u16)bf16_rn(val - __uint_as_float(hbits << 16));
            }
    }
}

// ============ OUT GEMM: out[8192,256] = Ab * Wo^T + b, planes + gload_lds ============
__global__ __launch_bounds__(256) void out_proj_kernel(
    const u16* __restrict__ Ahp, const u16* __restrict__ Alp,
    const u16* __restrict__ Wh, const u16* __restrict__ Wl,
    const float* __restrict__ bias, float* __restrict__ C)
{
    __shared__ __align__(16) u16 SA[2][2][64 * BK];
    __shared__ __align__(16) u16 SB[2][2][64 * BK];
    const int tid = threadIdx.x;
    const int wg0 = blockIdx.y * 4 + blockIdx.x;     // 512 blocks, 512 % 8 == 0
    const int wg = (wg0 & 7) * 64 + (wg0 >> 3);
    const int n0 = (wg & 3) * 64, m0 = (wg >> 2) * 64;
    const int lane = tid & 63, wv = tid >> 6;
    const int lm = lane & 15, kq = lane >> 4;
    const int gr = lane >> 2;
    const int gc = ((lane & 3) ^ ((lane >> 3) & 3)) * 8;
    const int swz = (lm >> 1) & 3;
    const int wm = (wv >> 1) * 32, wn = (wv & 1) * 32;

    auto stage = [&](int buf, int k0) {
        const size_t arow = (size_t)(m0 + 16 * wv + gr) * EMB + k0 + gc;
        gload16(Ahp + arow, &SA[buf][0][wv * 512]);
        gload16(Alp + arow, &SA[buf][1][wv * 512]);
        const size_t brow = (size_t)(n0 + 16 * wv + gr) * EMB + k0 + gc;
        gload16(Wh + brow, &SB[buf][0][wv * 512]);
        gload16(Wl + brow, &SB[buf][1][wv * 512]);
    };

    floatx4 acc[2][2] = {};
    stage(0, 0);
    __syncthreads();
    int cur = 0;
    for (int t = 0; t < 8; ++t) {
        if (t < 7) stage(cur ^ 1, (t + 1) * 32);
        short8 a_h[2], a_l[2], b_h[2], b_l[2];
#pragma unroll
        for (int mt = 0; mt < 2; ++mt) {
            const int ro = (wm + mt * 16 + lm) * BK + (kq ^ swz) * 8;
            a_h[mt] = *(const short8*)&SA[cur][0][ro];
            a_l[mt] = *(const short8*)&SA[cur][1][ro];
        }
#pragma unroll
        for (int nt = 0; nt < 2; ++nt) {
            const int ro = (wn + nt * 16 + lm) * BK + (kq ^ swz) * 8;
            b_h[nt] = *(const short8*)&SB[cur][0][ro];
            b_l[nt] = *(const short8*)&SB[cur][1][ro];
        }
#pragma unroll
        for (int mt = 0; mt < 2; ++mt)
#pragma unroll
            for (int nt = 0; nt < 2; ++nt) {
                acc[mt][nt] = __builtin_amdgcn_mfma_f32_16x16x32_bf16(a_h[mt], b_h[nt], acc[mt][nt], 0, 0, 0);
                acc[mt][nt] = __builtin_amdgcn_mfma_f32_16x16x32_bf16(a_h[mt], b_l[nt], acc[mt][nt], 0, 0, 0);
                acc[mt][nt] = __builtin_amdgcn_mfma_f32_16x16x32_bf16(a_l[mt], b_h[nt], acc[mt][nt], 0, 0, 0);
            }
        __syncthreads();
        cur ^= 1;
    }
#pragma unroll
    for (int nt = 0; nt < 2; ++nt) {
        const int f = n0 + wn + nt * 16 + lm;
        const float bf = bias[f];
#pragma unroll
        for (int mt = 0; mt < 2; ++mt)
#pragma unroll
            for (int r = 0; r < 4; ++r) {
                const int m = m0 + wm + mt * 16 + kq * 4 + r;
                C[(size_t)m * EMB + f] = acc[mt][nt][r] + bf;
            }
    }
}

// ================= Banded attention (swapped-QK, in-register softmax, plane I/O) =================
#define AKS 40   // K row stride (u16)
#define AVS 200  // Vt row stride (u16)

__global__ __launch_bounds__(256) void local_attn_kernel(
    const u16* __restrict__ Qhg, const u16* __restrict__ Qlg,
    const u16* __restrict__ Khg, const u16* __restrict__ Klg,
    const u16* __restrict__ Vhg,
    u16* __restrict__ Abh, u16* __restrict__ Abl)
{
    __shared__ __align__(16) u16 sKh[192 * AKS], sKl[192 * AKS];
    __shared__ __align__(16) u16 sVt[32 * AVS];

    const int tid = threadIdx.x;
    const int q0 = blockIdx.x * 64;
    const int h = blockIdx.y, b = blockIdx.z;
    const int jmin = max(0, q0 - WIN);
    const int jmax = min(S_LEN - 1, q0 + 63 + WIN);
    const int nk = jmax - jmin + 1;                  // <= 192
    const size_t bhS = ((size_t)b * NHEAD + h) * S_LEN;
    const size_t qoff = (bhS + q0) * HDIM;
    const size_t koff = (bhS + jmin) * HDIM;

    const int lane = tid & 63, wv = tid >> 6;
    const int lm = lane & 15, quad = lane >> 4;
    const int qbase = wv * 16;

    // Q to registers: direct plane loads, no unpack
    const short8 qh = *(const short8*)(Qhg + qoff + (size_t)(qbase + lm) * HDIM + quad * 8);
    const short8 ql = *(const short8*)(Qlg + qoff + (size_t)(qbase + lm) * HDIM + quad * 8);

    const int srow = tid >> 2, sc = tid & 3;
    // stage K (192 slots): direct plane copies, tail clamped (masked later)
#pragma unroll
    for (int r = 0; r < 3; ++r) {
        const int t = srow + r * 64;
        const int tc = min(t, nk - 1);
        const size_t go = koff + (size_t)tc * HDIM + sc * 8;
        *(short8*)&sKh[t * AKS + sc * 8] = *(const short8*)(Khg + go);
        *(short8*)&sKl[t * AKS + sc * 8] = *(const short8*)(Klg + go);
    }
    // stage V transposed (hi plane): Vt[dim][slot]
#pragma unroll
    for (int r = 0; r < 3; ++r) {
        const int t = srow + r * 64;
        const int tc = min(t, nk - 1);
        const short8 v = *(const short8*)(Vhg + koff + (size_t)tc * HDIM + sc * 8);
        const int d0 = sc * 8;
#pragma unroll
        for (int j = 0; j < 8; ++j)
            sVt[(d0 + j) * AVS + t] = (u16)v[j];
    }
    __syncthreads();

    // band-aware tile window: 10 tiles suffice (vs 12)
    const int tb = max(0, ((wv >> 1) << 1) + (min(q0 - WIN, 0) >> 4));

    floatx4 sacc[10];
#pragma unroll
    for (int i = 0; i < 10; ++i) {
        const int nt = tb + i;
        const short8 kh = *(const short8*)&sKh[(nt * 16 + lm) * AKS + quad * 8];
        const short8 kl = *(const short8*)&sKl[(nt * 16 + lm) * AKS + quad * 8];
        floatx4 a = {};
        a = __builtin_amdgcn_mfma_f32_16x16x32_bf16(kh, qh, a, 0, 0, 0);
        a = __builtin_amdgcn_mfma_f32_16x16x32_bf16(kh, ql, a, 0, 0, 0);
        a = __builtin_amdgcn_mfma_f32_16x16x32_bf16(kl, qh, a, 0, 0, 0);
        sacc[i] = a;
    }

    // mask + row max (row = this lane's q = q0+qbase+lm)
    const int qr = q0 + qbase + lm;
    float mx = -1e30f;
#pragma unroll
    for (int i = 0; i < 10; ++i) {
        const int sbase = (tb + i) * 16 + quad * 4;
#pragma unroll
        for (int r = 0; r < 4; ++r) {
            const int slot = sbase + r;
            const int keyg = jmin + slot;
            const bool valid = (slot < nk) && (keyg >= qr - WIN) && (keyg <= qr + WIN);
            const float sv = valid ? sacc[i][r] : -1e30f;
            sacc[i][r] = sv;
            mx = fmaxf(mx, sv);
        }
    }
    mx = fmaxf(mx, __shfl_xor(mx, 16));
    mx = fmaxf(mx, __shfl_xor(mx, 32));

    // exp + sum + pack P to bf16 in-register (unnormalized; rl applied at epilogue)
    float l = 0.f;
    u32 pk_[20];
#pragma unroll
    for (int i = 0; i < 10; ++i) {
        const float p0 = __expf(sacc[i][0] - mx);
        const float p1 = __expf(sacc[i][1] - mx);
        const float p2 = __expf(sacc[i][2] - mx);
        const float p3 = __expf(sacc[i][3] - mx);
        l += (p0 + p1) + (p2 + p3);
        pk_[2 * i]     = bf16_rn(p0) | (bf16_rn(p1) << 16);
        pk_[2 * i + 1] = bf16_rn(p2) | (bf16_rn(p3) << 16);
    }
    l += __shfl_xor(l, 16);
    l += __shfl_xor(l, 32);
    const float rl = 1.f / l;

    // PV with k-permutation pi; ks range [kb, kb+5) covers exactly tiles [tb, tb+10)
    const int kb = tb >> 1;
    floatx4 oacc[2] = {};
#pragma unroll
    for (int i = 0; i < 5; ++i) {
        const int ks = kb + i;
        uint4 aw;
        aw.x = pk_[4 * i + 0];
        aw.y = pk_[4 * i + 1];
        aw.z = pk_[4 * i + 2];
        aw.w = pk_[4 * i + 3];
        const short8 ap = *(const short8*)&aw;
        const int sb = ks * 32 + quad * 4;
        const uint2 e0 = *(const uint2*)&sVt[lm * AVS + sb];
        const uint2 o0 = *(const uint2*)&sVt[lm * AVS + sb + 16];
        const uint2 e1 = *(const uint2*)&sVt[(16 + lm) * AVS + sb];
        const uint2 o1 = *(const uint2*)&sVt[(16 + lm) * AVS + sb + 16];
        uint4 bw0; bw0.x = e0.x; bw0.y = e0.y; bw0.z = o0.x; bw0.w = o0.y;
        uint4 bw1; bw1.x = e1.x; bw1.y = e1.y; bw1.z = o1.x; bw1.w = o1.y;
        const short8 bv0 = *(const short8*)&bw0;
        const short8 bv1 = *(const short8*)&bw1;
        oacc[0] = __builtin_amdgcn_mfma_f32_16x16x32_bf16(ap, bv0, oacc[0], 0, 0, 0);
        oacc[1] = __builtin_amdgcn_mfma_f32_16x16x32_bf16(ap, bv1, oacc[1], 0, 0, 0);
    }

    // epilogue: lane (lm,quad) holds O[q=quad*4+r][d=nt*16+lm]; hi/lo plane stores
    float rlr[4];
#pragma unroll
    for (int r = 0; r < 4; ++r) rlr[r] = __shfl(rl, quad * 4 + r);
#pragma unroll
    for (int nt = 0; nt < 2; ++nt)
#pragma unroll
        for (int r = 0; r < 4; ++r) {
            const int qrow = qbase + quad * 4 + r;
            const float o = oacc[nt][r] * rlr[r];
            const u32 hb = bf16_rn(o);
            const size_t idx = ((size_t)b * S_LEN + q0 + qrow) * EMB + h * HDIM + nt * 16 + lm;
            Abh[idx] = (u16)hb;
            Abl[idx] = (u16)bf16_rn(o - __uint_as_float(hb << 16));
        }
}

extern "C" void kernel_launch(void* const* d_in, const int* in_sizes, int n_in,
                              void* d_out, int out_size, void* d_ws, size_t ws_size,
                              hipStream_t stream) {
    const float* x  = (const float*)d_in[0];
    const float* wi = (const float*)d_in[1];
    const float* bi = (const float*)d_in[2];
    const float* wo = (const float*)d_in[3];
    const float* bo = (const float*)d_in[4];
    float* out = (float*)d_out;

    const size_t per = (size_t)BATCH * NHEAD * S_LEN * HDIM; // 2,097,152
    u16* p = (u16*)d_ws;
    u16* Xh  = p; p += per;
    u16* Xl  = p; p += per;
    u16* Wih = p; p += 768 * EMB;
    u16* Wil = p; p += 768 * EMB;
    u16* Woh = p; p += EMB * EMB;
    u16* Wol = p; p += EMB * EMB;
    u16* Qh  = p; p += per;
    u16* Ql  = p; p += per;
    u16* Kh  = p; p += per;
    u16* Kl  = p; p += per;
    u16* Vh  = p; p += per;
    u16* Abh = p; p += per;
    u16* Abl = p; p += per;

    convert_kernel<<<dim3((NX4 + NW4 + NO4) / 256), 256, 0, stream>>>(
        x, wi, wo, Xh, Xl, Wih, Wil, Woh, Wol);
    qkv_proj_kernel<<<dim3(768 / 64, 8192 / 128), 256, 0, stream>>>(
        Xh, Xl, Wih, Wil, bi, Qh, Ql, Kh, Kl, Vh);
    local_attn_kernel<<<dim3(S_LEN / 64, NHEAD, BATCH), 256, 0, stream>>>(
        Qh, Ql, Kh, Kl, Vh, Abh, Abl);
    out_proj_kernel<<<dim3(256 / 64, 8192 / 64), 256, 0, stream>>>(
        Abh, Abl, Woh, Wol, bo, out);
}